// Round 14
// baseline (156.846 us; speedup 1.0000x reference)
//
#include <hip/hip_runtime.h>
#include <hip/hip_bf16.h>

#define C_  19
#define D_  512
#define H_  4
#define DH_ 128
#define NROW 65536
#define CHP_ 96
#define WPITCH 104   // u16 per WaL row (208B, 16B-aligned)

typedef float f32x4 __attribute__((ext_vector_type(4)));
typedef short bf16x8 __attribute__((ext_vector_type(8)));

__device__ __forceinline__ unsigned short f2bf(float f) {
  union { __hip_bfloat16 h; unsigned short s; } u;
  u.h = __float2bfloat16(f);
  return u.s;
}
__device__ __forceinline__ bf16x8 ld_cvt8(const float* p) {
  f32x4 v0 = *(const f32x4*)p;
  f32x4 v1 = *(const f32x4*)(p + 4);
  bf16x8 a;
  a[0]=(short)f2bf(v0[0]); a[1]=(short)f2bf(v0[1]);
  a[2]=(short)f2bf(v0[2]); a[3]=(short)f2bf(v0[3]);
  a[4]=(short)f2bf(v1[0]); a[5]=(short)f2bf(v1[1]);
  a[6]=(short)f2bf(v1[2]); a[7]=(short)f2bf(v1[3]);
  return a;
}

// ---- prep (r13-verbatim): K/V in-block, Mtf/Utf frag-order, bo at p=80 ----
__global__ __launch_bounds__(512) void prep(
    const float* __restrict__ ce,
    const float* __restrict__ Wq, const float* __restrict__ bq,
    const float* __restrict__ Wk, const float* __restrict__ bk,
    const float* __restrict__ Wv, const float* __restrict__ bv,
    const float* __restrict__ Wo, const float* __restrict__ bo,
    unsigned short* __restrict__ Mtf, unsigned short* __restrict__ Utf,
    float* __restrict__ s0g)
{
  __shared__ float KV[2][DH_];
  __shared__ float KVp[512];

  const int p = blockIdx.x;   // 0..95
  const int m = threadIdx.x;  // 0..511
  const int mt_off = (p>>4)*8192 + (m>>5)*512 + ((((m>>3)&3)<<4) + (p&15))*8 + (m&7);
  const int ut_off = ((m>>4)*3 + (p>>5))*512 + ((((p>>3)&3)<<4) + (m&15))*8 + (p&7);
  const int c = p >> 2, h = p & 3;

  if (c >= C_) {   // dead slots; p==80 carries bo (Wa col 80 is 1.0)
    if (p < 80) { Mtf[mt_off] = 0; if (m == 0) s0g[p] = 0.f; }
    Utf[ut_off] = (p == 80) ? f2bf(bo[m]) : (unsigned short)0;
    return;
  }

  {
    const int which = m >> 8;            // 0:K 1:V
    const int dh    = (m >> 1) & 127;
    const int half  = m & 1;
    const float* w = (which ? Wv : Wk) + (size_t)(h*DH_ + dh)*D_ + half*256;
    const float* e = ce + (size_t)c*D_ + half*256;
    float acc = 0.f;
    #pragma unroll 8
    for (int d = 0; d < 256; ++d) acc = fmaf(e[d], w[d], acc);
    KVp[m] = acc;
  }
  __syncthreads();
  if (m < 256) {
    const int which = m >> 7, dh = m & 127;
    KV[which][dh] = KVp[2*m] + KVp[2*m+1] + (which ? bv : bk)[h*DH_ + dh];
  }
  __syncthreads();

  const float rs128 = 0.08838834764831843f;  // 1/sqrt(128)
  float macc = 0.f;
  #pragma unroll 4
  for (int dh = 0; dh < DH_; ++dh)
    macc = fmaf(Wq[(size_t)(h*DH_+dh)*D_ + m], KV[0][dh], macc);
  Mtf[mt_off] = f2bf(macc * rs128);

  float uacc = 0.f;
  const float* wor = Wo + (size_t)m*D_ + h*DH_;
  #pragma unroll 4
  for (int dh = 0; dh < DH_; ++dh)
    uacc = fmaf(wor[dh], KV[1][dh], uacc);
  Utf[ut_off] = f2bf(uacc);

  if (m == 0) {
    float sa = 0.f;
    for (int dh = 0; dh < DH_; ++dh) sa = fmaf(bq[h*DH_+dh], KV[0][dh], sa);
    s0g[p] = sa * rs128;
  }
}

// ---- fused256: 256 rows/block, 8 waves, 1 block/CU, ONE barrier -----------
// Utf staged to LDS once (shared). Phase 1 operand-SWAPPED: A=Mtf (one read
// per 32 rows), B=x rows. S^T softmax: h=r, c=mtile*4+lhi, xor(16,32).
// Phase 3: A=WaL (own rows), B=Utf from LDS. Residual: x re-read (L3-hot).
__global__ __launch_bounds__(512, 2) void fused256(
    const float* __restrict__ x,
    const unsigned short* __restrict__ Mtf,  // frag-ordered [5][16][64][8]
    const unsigned short* __restrict__ Utf,  // frag-ordered [32][3][64][8]
    const float* __restrict__ s0g,           // [80] permuted
    const float* __restrict__ gamma, const float* __restrict__ beta,
    float* __restrict__ out)
{
  __shared__ __attribute__((aligned(16))) unsigned short UtfL[CHP_*512]; // 96KB
  __shared__ __attribute__((aligned(16))) unsigned short WaL[256][WPITCH]; // 52KB

  const int t    = threadIdx.x;
  const int w    = t >> 6;
  const int lane = t & 63;
  const int lhi  = lane >> 4;
  const int llo  = lane & 15;
  const int row0 = blockIdx.x * 256;
  const int wr   = w * 32;               // wave's local row base

  // ---- stage Utf -> LDS (96KB, coalesced; completes before the barrier) ----
  #pragma unroll
  for (int i = 0; i < 12; ++i) {
    int off = i*8192 + t*16;             // bytes
    *(bf16x8*)((char*)UtfL + off) = *(const bf16x8*)((const char*)Utf + off);
  }

  // ---- phase 1 (swapped): S^T[80][32 rows] ; A=Mtf, B=x rows --------------
  f32x4 acc[5][2];
  #pragma unroll
  for (int m = 0; m < 5; ++m)
    #pragma unroll
    for (int j = 0; j < 2; ++j) acc[m][j] = (f32x4){0,0,0,0};
  {
    const float* xr0 = x + (size_t)(row0 + wr      + llo)*D_ + lhi*8;
    const float* xr1 = x + (size_t)(row0 + wr + 16 + llo)*D_ + lhi*8;
    #pragma unroll
    for (int ks = 0; ks < 16; ++ks) {
      bf16x8 xb0 = ld_cvt8(xr0 + ks*32);
      bf16x8 xb1 = ld_cvt8(xr1 + ks*32);
      #pragma unroll
      for (int m = 0; m < 5; ++m) {
        bf16x8 a = *(const bf16x8*)(Mtf + m*8192 + ks*512 + lane*8);
        acc[m][0] = __builtin_amdgcn_mfma_f32_16x16x32_bf16(a, xb0, acc[m][0], 0, 0, 0);
        acc[m][1] = __builtin_amdgcn_mfma_f32_16x16x32_bf16(a, xb1, acc[m][1], 0, 0, 0);
      }
    }
  }
  // acc[m][t2][r] = S^T[p = m*16 + lhi*4 + r][xrow = wr + t2*16 + llo]

  // ---- softmax on S^T: h = r, c = m*4 + lhi; reduce in-reg + xor(16,32) ----
  {
    const bool dead = (lhi == 3);        // c = 4*4+3 = 19 for m=4
    #pragma unroll
    for (int t2 = 0; t2 < 2; ++t2) {
      #pragma unroll
      for (int r = 0; r < 4; ++r) {
        float v0 = acc[0][t2][r] + s0g[ 0 + lhi*4 + r];
        float v1 = acc[1][t2][r] + s0g[16 + lhi*4 + r];
        float v2 = acc[2][t2][r] + s0g[32 + lhi*4 + r];
        float v3 = acc[3][t2][r] + s0g[48 + lhi*4 + r];
        float v4 = dead ? -1e30f : (acc[4][t2][r] + s0g[64 + lhi*4 + r]);
        float mx = fmaxf(fmaxf(fmaxf(v0, v1), fmaxf(v2, v3)), v4);
        mx = fmaxf(mx, __shfl_xor(mx, 16, 64));
        mx = fmaxf(mx, __shfl_xor(mx, 32, 64));
        float e0 = __expf(v0 - mx), e1 = __expf(v1 - mx), e2 = __expf(v2 - mx),
              e3 = __expf(v3 - mx), e4 = dead ? 0.f : __expf(v4 - mx);
        float sm = e0 + e1 + e2 + e3 + e4;
        sm += __shfl_xor(sm, 16, 64);
        sm += __shfl_xor(sm, 32, 64);
        float inv = 1.f / sm;
        int xr = wr + t2*16 + llo;
        WaL[xr][ 0 + lhi*4 + r] = f2bf(e0 * inv);
        WaL[xr][16 + lhi*4 + r] = f2bf(e1 * inv);
        WaL[xr][32 + lhi*4 + r] = f2bf(e2 * inv);
        WaL[xr][48 + lhi*4 + r] = f2bf(e3 * inv);
        WaL[xr][64 + lhi*4 + r] = f2bf(e4 * inv);
      }
    }
    // pad cols 80..95: col 80 = 1.0 (bo slot), rest 0
    {
      int rr = wr + (lane & 31);
      int cb = 80 + (lane >> 5) * 8;
      bf16x8 z = (bf16x8){0,0,0,0,0,0,0,0};
      if (cb == 80) z[0] = (short)0x3F80;
      *(bf16x8*)&WaL[rr][cb] = z;
    }
  }
  __syncthreads();   // the ONLY barrier: UtfL (+WaL) visible

  // ---- phase 3 + epilogue: 2 passes of 16 rows (wave's own rows) ----------
  #pragma unroll 1
  for (int pp = 0; pp < 2; ++pp) {
    const int base = wr + pp*16;
    f32x4 oacc[32];
    #pragma unroll
    for (int i = 0; i < 32; ++i) oacc[i] = (f32x4){0,0,0,0};
    #pragma unroll
    for (int ks = 0; ks < 3; ++ks) {
      bf16x8 a = *(const bf16x8*)&WaL[base + llo][ks*32 + lhi*8];
      #pragma unroll
      for (int tl = 0; tl < 32; ++tl) {
        bf16x8 b = *(const bf16x8*)((const char*)UtfL + (size_t)(tl*3 + ks)*1024 + lane*16);
        oacc[tl] = __builtin_amdgcn_mfma_f32_16x16x32_bf16(a, b, oacc[tl], 0, 0, 0);
      }
    }
    // oacc[tl][r] = (attn+bo)[m = base+lhi*4+r][n = tl*16 + llo]

    float s[4] = {0,0,0,0}, q[4] = {0,0,0,0};
    #pragma unroll
    for (int tl = 0; tl < 32; ++tl) {
      int n = tl*16 + llo;
      #pragma unroll
      for (int r = 0; r < 4; ++r) {
        int mr = base + lhi*4 + r;
        float val = oacc[tl][r] + x[(size_t)(row0 + mr)*D_ + n];
        oacc[tl][r] = val;
        s[r] += val;
        q[r] = fmaf(val, val, q[r]);
      }
    }
    #pragma unroll
    for (int r = 0; r < 4; ++r) {
      #pragma unroll
      for (int off = 1; off < 16; off <<= 1) {
        s[r] += __shfl_xor(s[r], off, 64);
        q[r] += __shfl_xor(q[r], off, 64);
      }
    }
    float mu_r[4], rstd_r[4];
    #pragma unroll
    for (int r = 0; r < 4; ++r) {
      float mu  = s[r] * (1.f/(float)D_);
      float var = q[r] * (1.f/(float)D_) - mu*mu;
      mu_r[r]   = mu;
      rstd_r[r] = rsqrtf(var + 1e-5f);
    }
    #pragma unroll
    for (int tl = 0; tl < 32; ++tl) {
      int n = tl*16 + llo;
      float g = gamma[n], bt = beta[n];
      #pragma unroll
      for (int r = 0; r < 4; ++r) {
        int mr = base + lhi*4 + r;
        out[(size_t)(row0 + mr)*D_ + n] = (oacc[tl][r] - mu_r[r]) * rstd_r[r] * g + bt;
      }
    }
  }
}

extern "C" void kernel_launch(void* const* d_in, const int* in_sizes, int n_in,
                              void* d_out, int out_size, void* d_ws, size_t ws_size,
                              hipStream_t stream) {
  const float* x     = (const float*)d_in[0];
  const float* ce    = (const float*)d_in[1];
  const float* Wq    = (const float*)d_in[2];
  const float* bq    = (const float*)d_in[3];
  const float* Wk    = (const float*)d_in[4];
  const float* bk    = (const float*)d_in[5];
  const float* Wv    = (const float*)d_in[6];
  const float* bv    = (const float*)d_in[7];
  const float* Wo    = (const float*)d_in[8];
  const float* bo    = (const float*)d_in[9];
  const float* gamma = (const float*)d_in[10];
  const float* beta  = (const float*)d_in[11];
  float* out = (float*)d_out;

  char* ws = (char*)d_ws;
  unsigned short* Mtf = (unsigned short*)(ws);           // 80*512*2 = 81920
  unsigned short* Utf = (unsigned short*)(ws + 81920);   // 512*96*2 = 98304
  float* s0g          = (float*)(ws + 180224);           // 320

  prep<<<CHP_, 512, 0, stream>>>(ce, Wq, bq, Wk, bk, Wv, bv, Wo, bo,
                                 Mtf, Utf, s0g);
  fused256<<<NROW/256, 512, 0, stream>>>(x, Mtf, Utf, s0g, gamma, beta, out);
}